// Round 8
// baseline (663.748 us; speedup 1.0000x reference)
//
#include <hip/hip_runtime.h>
#include <math.h>

static constexpr int N = 20000;       // nodes
static constexpr int E = 8192;        // hyperedges
static constexpr int F = 128;         // feature dim
static constexpr int NP = 20480;      // padded node count (K for gemmB; 1024*20)
static constexpr int NP2 = 20096;     // padded node count for gemmC output planes (157*128)
static constexpr int PREP_REAL = 1000;    // blocks of k_prep carrying real rows (20 each)
static constexpr int KS_B = 8;        // gemmB split-K
static constexpr int KS_C = 4;        // gemmC split-K

typedef short bf16x8 __attribute__((ext_vector_type(8)));
typedef float f32x4 __attribute__((ext_vector_type(4)));

__device__ __forceinline__ float gelu_erf(float x) {
    return 0.5f * x * (1.0f + erff(x * 0.70710678118654752440f));
}
__device__ __forceinline__ ushort f2bf(float f) {
    unsigned u = __float_as_uint(f);
    return (ushort)((u + 0x7FFFu + ((u >> 16) & 1u)) >> 16);
}

// ---------------- lwT[k][f] = lin_w[f][k] ----------------
__global__ void k_transpose_lw(const float* __restrict__ lin_w, float* __restrict__ lwT) {
    int idx = blockIdx.x * 256 + threadIdx.x;
    if (idx < F * F) {
        int k = idx >> 7, f = idx & 127;
        lwT[idx] = lin_w[f * F + k];
    }
}

// ---------------- prep: stream H -> Dv, DeP (col partials), Hbs = bf16(H) ----------------
__global__ void k_prep(const float* __restrict__ H, float* __restrict__ Dv,
                       float* __restrict__ DeP, ushort* __restrict__ Hbs) {
    const int tid = threadIdx.x, lane = tid & 63, wid = tid >> 6;
    const int r0 = blockIdx.x * 20;
    if (r0 >= N) {            // pad rows [N, NP): Hbs = 0
        ushort4 z = make_ushort4(0, 0, 0, 0);
        for (int r = 0; r < 20; ++r) {
            ushort* orow = Hbs + (size_t)(r0 + r) * E;
#pragma unroll
            for (int j = 0; j < 8; ++j) *(ushort4*)(orow + j * 1024 + tid * 4) = z;
        }
        return;
    }
    __shared__ float rp[20][4];
    float4 ca[8];
#pragma unroll
    for (int j = 0; j < 8; ++j) ca[j] = make_float4(0.f, 0.f, 0.f, 0.f);
    for (int r = 0; r < 20; ++r) {
        const float* row = H + (size_t)(r0 + r) * E;
        ushort* orow = Hbs + (size_t)(r0 + r) * E;
        float rs = 0.f;
#pragma unroll
        for (int j = 0; j < 8; ++j) {
            float4 v = *(const float4*)(row + j * 1024 + tid * 4);
            ca[j].x += v.x; ca[j].y += v.y; ca[j].z += v.z; ca[j].w += v.w;
            rs += (v.x + v.y) + (v.z + v.w);
            ushort4 b;
            b.x = f2bf(v.x); b.y = f2bf(v.y); b.z = f2bf(v.z); b.w = f2bf(v.w);
            *(ushort4*)(orow + j * 1024 + tid * 4) = b;
        }
#pragma unroll
        for (int off = 32; off > 0; off >>= 1) rs += __shfl_xor(rs, off, 64);
        if (lane == 0) rp[r][wid] = rs;
    }
    __syncthreads();
    if (tid < 20) Dv[r0 + tid] = rp[tid][0] + rp[tid][1] + rp[tid][2] + rp[tid][3];
    float* dp = DeP + (size_t)blockIdx.x * E;
#pragma unroll
    for (int j = 0; j < 8; ++j) *(float4*)(dp + j * 1024 + tid * 4) = ca[j];
}

// ---------------- se[e] = W[e] / clip(sum_p DeP[p][e], 1) ----------------
__global__ void k_se(const float* __restrict__ DeP, const float* __restrict__ W,
                     float* __restrict__ se) {
    __shared__ float red[4][64];
    const int tid = threadIdx.x;
    const int c = blockIdx.x * 64 + (tid & 63);
    const int pg = tid >> 6;
    float s = 0.f;
    for (int p = pg; p < PREP_REAL; p += 4) s += DeP[(size_t)p * E + c];
    red[pg][tid & 63] = s;
    __syncthreads();
    if (tid < 64) {
        float d = red[0][tid] + red[1][tid] + red[2][tid] + red[3][tid];
        int e = blockIdx.x * 64 + tid;
        se[e] = W[e] / fmaxf(d, 1.f);
    }
}

// ---------------- y[v][f] = bf16(dvis[v] * (x@lw^T + b)) ----------------
__global__ void k_xw(const float* __restrict__ x, const float* __restrict__ lwT,
                     const float* __restrict__ lin_b, const float* __restrict__ Dv,
                     ushort* __restrict__ y) {
    __shared__ __align__(16) float xs[4][F];
    int f = threadIdx.x;            // 128 threads
    int r0 = blockIdx.x * 4;
    if (r0 >= N) {
#pragma unroll
        for (int j = 0; j < 4; ++j) y[(size_t)(r0 + j) * F + f] = 0;
        return;
    }
#pragma unroll
    for (int j = 0; j < 4; ++j) xs[j][f] = x[(size_t)(r0 + j) * F + f];
    __syncthreads();
    float s0 = rsqrtf(fmaxf(Dv[r0 + 0], 1.f));
    float s1 = rsqrtf(fmaxf(Dv[r0 + 1], 1.f));
    float s2 = rsqrtf(fmaxf(Dv[r0 + 2], 1.f));
    float s3 = rsqrtf(fmaxf(Dv[r0 + 3], 1.f));
    float b = lin_b[f];
    float a0 = b, a1 = b, a2 = b, a3 = b;
#pragma unroll 4
    for (int k = 0; k < F; ++k) {
        float lw = lwT[k * F + f];
        a0 += xs[0][k] * lw;
        a1 += xs[1][k] * lw;
        a2 += xs[2][k] * lw;
        a3 += xs[3][k] * lw;
    }
    y[(size_t)(r0 + 0) * F + f] = f2bf(s0 * a0);
    y[(size_t)(r0 + 1) * F + f] = f2bf(s1 * a1);
    y[(size_t)(r0 + 2) * F + f] = f2bf(s2 * a2);
    y[(size_t)(r0 + 3) * F + f] = f2bf(s3 * a3);
}

// ---------------- yT[f][v] = y[v][f]  (bf16 64x64 tile transpose) ----------------
__global__ void k_ytrans(const ushort* __restrict__ y, ushort* __restrict__ yT) {
    __shared__ __align__(16) char tl[8192];
    int tid = threadIdx.x;
    int r0 = (blockIdx.x >> 1) * 64;   // v
    int c0 = (blockIdx.x & 1) * 64;    // f
#pragma unroll
    for (int c = 0; c < 2; ++c) {
        int lin = c * 256 + tid;
        int row = lin >> 3, ch = lin & 7;
        uint4 v = *(const uint4*)(y + (size_t)(r0 + row) * F + c0 + ch * 8);
        int key = ((row ^ (row >> 3)) & 7) << 4;
        *(uint4*)(tl + row * 128 + ((ch * 16) ^ key)) = v;
    }
    __syncthreads();
#pragma unroll
    for (int c = 0; c < 2; ++c) {
        int lin = c * 256 + tid;
        int fl = lin >> 3, vch = lin & 7;
        unsigned u[4];
#pragma unroll
        for (int qq = 0; qq < 4; ++qq) {
            int r1 = vch * 8 + qq * 2, r2 = r1 + 1;
            ushort a = *(const ushort*)(tl + r1 * 128 + ((fl * 2) ^ (((r1 ^ (r1 >> 3)) & 7) << 4)));
            ushort b = *(const ushort*)(tl + r2 * 128 + ((fl * 2) ^ (((r2 ^ (r2 >> 3)) & 7) << 4)));
            u[qq] = (unsigned)a | ((unsigned)b << 16);
        }
        uint4 o = make_uint4(u[0], u[1], u[2], u[3]);
        *(uint4*)(yT + (size_t)(c0 + fl) * NP + r0 + vch * 8) = o;
    }
}

// ---------------- tsT[f][e] = bf16(se[e] * sum_ks tB[ks][e][f])  (reduce + transpose) ------
__global__ void k_tst(const float* __restrict__ tB, const float* __restrict__ se,
                      ushort* __restrict__ tsT) {
    __shared__ __align__(16) char tl[8192];
    int tid = threadIdx.x;
    int r0 = (blockIdx.x >> 1) * 64;   // e
    int c0 = (blockIdx.x & 1) * 64;    // f
#pragma unroll
    for (int c = 0; c < 4; ++c) {
        int lin = c * 256 + tid;
        int row = lin >> 4, ch = lin & 15;
        size_t base = (size_t)(r0 + row) * F + c0 + ch * 4;
        float4 v = make_float4(0.f, 0.f, 0.f, 0.f);
#pragma unroll
        for (int ks = 0; ks < KS_B; ++ks) {
            float4 p = *(const float4*)(tB + (size_t)ks * E * F + base);
            v.x += p.x; v.y += p.y; v.z += p.z; v.w += p.w;
        }
        float s = se[r0 + row];
        ushort4 b;
        b.x = f2bf(v.x * s); b.y = f2bf(v.y * s); b.z = f2bf(v.z * s); b.w = f2bf(v.w * s);
        int key = ((row ^ (row >> 3)) & 7) << 4;
        *(ushort4*)(tl + row * 128 + ((ch * 8) ^ key)) = b;
    }
    __syncthreads();
#pragma unroll
    for (int c = 0; c < 2; ++c) {
        int lin = c * 256 + tid;
        int fl = lin >> 3, vch = lin & 7;
        unsigned u[4];
#pragma unroll
        for (int qq = 0; qq < 4; ++qq) {
            int r1 = vch * 8 + qq * 2, r2 = r1 + 1;
            ushort a = *(const ushort*)(tl + r1 * 128 + ((fl * 2) ^ (((r1 ^ (r1 >> 3)) & 7) << 4)));
            ushort b = *(const ushort*)(tl + r2 * 128 + ((fl * 2) ^ (((r2 ^ (r2 >> 3)) & 7) << 4)));
            u[qq] = (unsigned)a | ((unsigned)b << 16);
        }
        uint4 o = make_uint4(u[0], u[1], u[2], u[3]);
        *(uint4*)(tsT + (size_t)(c0 + fl) * E + r0 + vch * 8) = o;
    }
}

// ---------------- gemmB (MFMA): tB[ks][e][f] = sum_{v in chunk} Hbs[v][e] * yT[f][v] ------
// A: LDS transpose-staged (dbuf, 1 barrier/step). B: DIRECT global->VGPR fragments (yT is
// k-contiguous); no LDS for B -> 32 KB LDS, ~3 blocks/CU, B loads never barrier-drained.
__global__ __launch_bounds__(256) void k_gemmB(const ushort* __restrict__ Hbs,
                                               const ushort* __restrict__ yT,
                                               float* __restrict__ tB) {
    __shared__ __align__(16) char lA[2][16384];   // As[e 128][v 64] bf16, key ((e>>3)&7)<<4
    const int tid = threadIdx.x;
    const int m0 = (blockIdx.x & 63) * 128;    // e tile
    const int ks = blockIdx.x >> 6;
    const int k0 = ks * 2560;                  // v chunk
    const int lane = tid & 63, w = tid >> 6;
    const int wm = (w & 1) * 64, wn = (w >> 1) * 64;
    const int lrow = lane & 15, g16 = (lane >> 4) * 16;
    const int NSTEP = 40;

    const int vq = tid >> 4;
    const int e8 = (tid & 15) * 8;
    const ushort* pa = Hbs + (size_t)(k0 + vq * 4) * E + m0 + e8;
    const int abase = e8 * 128 + ((vq * 8) ^ ((tid & 7) << 4));

    int aoff[4][2];
#pragma unroll
    for (int f = 0; f < 4; ++f)
#pragma unroll
        for (int kk = 0; kk < 2; ++kk) {
            int ma = wm + f * 16 + lrow;
            aoff[f][kk] = ma * 128 + (((kk * 64) + g16) ^ (((ma >> 3) & 7) << 4));
        }
    // direct B fragment pointers: yT[wn + j*16 + lrow][k0 + kt*64 + kk*32 + (lane>>4)*8]
    const ushort* pbv[4];
#pragma unroll
    for (int j = 0; j < 4; ++j)
        pbv[j] = yT + (size_t)(wn + j * 16 + lrow) * NP + k0 + (lane >> 4) * 8;

    f32x4 zero4 = {0.f, 0.f, 0.f, 0.f};
    f32x4 acc[4][4];
#pragma unroll
    for (int i = 0; i < 4; ++i)
#pragma unroll
        for (int j = 0; j < 4; ++j) acc[i][j] = zero4;

    uint4 ra[4];
    // prologue: A tile0 -> regs -> buf0; A tile1 -> regs; B(kt0,kk0) -> bvA
#pragma unroll
    for (int r = 0; r < 4; ++r) ra[r] = *(const uint4*)(pa + (size_t)r * E);
    {
        const ushort* u0 = (const ushort*)&ra[0];
        const ushort* u1 = (const ushort*)&ra[1];
        const ushort* u2 = (const ushort*)&ra[2];
        const ushort* u3 = (const ushort*)&ra[3];
#pragma unroll
        for (int i = 0; i < 8; ++i) {
            uint2 wv;
            wv.x = (unsigned)u0[i] | ((unsigned)u1[i] << 16);
            wv.y = (unsigned)u2[i] | ((unsigned)u3[i] << 16);
            *(uint2*)(lA[0] + abase + i * 128) = wv;
        }
    }
    pa += (size_t)64 * E;
#pragma unroll
    for (int r = 0; r < 4; ++r) ra[r] = *(const uint4*)(pa + (size_t)r * E);
    bf16x8 bvA[4], bvB[4];
#pragma unroll
    for (int j = 0; j < 4; ++j) bvA[j] = *(const bf16x8*)(pbv[j]);
    __syncthreads();

    for (int kt = 0; kt < NSTEP; ++kt) {
        const int cur = kt & 1;
        if (kt + 1 < NSTEP) {
            const ushort* u0 = (const ushort*)&ra[0];
            const ushort* u1 = (const ushort*)&ra[1];
            const ushort* u2 = (const ushort*)&ra[2];
            const ushort* u3 = (const ushort*)&ra[3];
#pragma unroll
            for (int i = 0; i < 8; ++i) {
                uint2 wv;
                wv.x = (unsigned)u0[i] | ((unsigned)u1[i] << 16);
                wv.y = (unsigned)u2[i] | ((unsigned)u3[i] << 16);
                *(uint2*)(lA[cur ^ 1] + abase + i * 128) = wv;
            }
        }
        if (kt + 2 < NSTEP) {
            pa += (size_t)64 * E;
#pragma unroll
            for (int r = 0; r < 4; ++r) ra[r] = *(const uint4*)(pa + (size_t)r * E);
        }
        // kk = 0: load bvB (this kt, kk1), compute with bvA
#pragma unroll
        for (int j = 0; j < 4; ++j) bvB[j] = *(const bf16x8*)(pbv[j] + kt * 64 + 32);
        {
            bf16x8 av[4];
#pragma unroll
            for (int f = 0; f < 4; ++f) av[f] = *(const bf16x8*)(lA[cur] + aoff[f][0]);
#pragma unroll
            for (int i = 0; i < 4; ++i)
#pragma unroll
                for (int j = 0; j < 4; ++j)
                    acc[i][j] = __builtin_amdgcn_mfma_f32_16x16x32_bf16(av[i], bvA[j], acc[i][j], 0, 0, 0);
        }
        // kk = 1: load bvA (next kt, kk0), compute with bvB
        if (kt + 1 < NSTEP) {
#pragma unroll
            for (int j = 0; j < 4; ++j) bvA[j] = *(const bf16x8*)(pbv[j] + (kt + 1) * 64);
        }
        {
            bf16x8 av[4];
#pragma unroll
            for (int f = 0; f < 4; ++f) av[f] = *(const bf16x8*)(lA[cur] + aoff[f][1]);
#pragma unroll
            for (int i = 0; i < 4; ++i)
#pragma unroll
                for (int j = 0; j < 4; ++j)
                    acc[i][j] = __builtin_amdgcn_mfma_f32_16x16x32_bf16(av[i], bvB[j], acc[i][j], 0, 0, 0);
        }
        if (kt + 1 < NSTEP) __syncthreads();
    }
    float* plane = tB + (size_t)ks * E * F;
    const int orow = (lane >> 4) * 4, ocol = lane & 15;
#pragma unroll
    for (int i = 0; i < 4; ++i)
#pragma unroll
        for (int j = 0; j < 4; ++j) {
            int gm = m0 + wm + i * 16 + orow;
            int gn = wn + j * 16 + ocol;
#pragma unroll
            for (int q = 0; q < 4; ++q)
                plane[(size_t)(gm + q) * F + gn] = acc[i][j][q];
        }
}

// ---------------- gemmC (MFMA): C2P[ks][n][f] = sum_{e in chunk} Hbs[n][e] * tsT[f][e] -----
// FULLY direct-load: both operands are k(=e)-contiguous -> global->VGPR fragments.
// NO LDS, NO barriers; 2-step register ping-pong (X even / Y odd steps of K=32).
__global__ __launch_bounds__(256) void k_gemmC(const ushort* __restrict__ Hbs,
                                               const ushort* __restrict__ tsT,
                                               float* __restrict__ C2P) {
    const int tid = threadIdx.x;
    const int m0 = (blockIdx.x % 157) * 128;
    const int ks = blockIdx.x / 157;
    const int k0 = ks * 2048;
    const int lane = tid & 63, w = tid >> 6;
    const int wm = (w & 1) * 64, wn = (w >> 1) * 64;
    const int lr = lane & 15, kg = (lane >> 4) * 8;

    const ushort* pa[4];
    const ushort* pb[4];
#pragma unroll
    for (int i = 0; i < 4; ++i) {
        pa[i] = Hbs + (size_t)(m0 + wm + i * 16 + lr) * E + k0 + kg;
        pb[i] = tsT + (size_t)(wn + i * 16 + lr) * E + k0 + kg;
    }

    f32x4 zero4 = {0.f, 0.f, 0.f, 0.f};
    f32x4 acc[4][4];
#pragma unroll
    for (int i = 0; i < 4; ++i)
#pragma unroll
        for (int j = 0; j < 4; ++j) acc[i][j] = zero4;

    bf16x8 xa[4], xb[4], ya[4], yb[4];
#pragma unroll
    for (int i = 0; i < 4; ++i) { xa[i] = *(const bf16x8*)pa[i]; xb[i] = *(const bf16x8*)pb[i]; }

    for (int kt = 0; kt < 64; kt += 2) {      // K-step 32, two per iter
        // load odd step
#pragma unroll
        for (int i = 0; i < 4; ++i) {
            ya[i] = *(const bf16x8*)(pa[i] + 32);
            yb[i] = *(const bf16x8*)(pb[i] + 32);
        }
#pragma unroll
        for (int i = 0; i < 4; ++i)
#pragma unroll
            for (int j = 0; j < 4; ++j)
                acc[i][j] = __builtin_amdgcn_mfma_f32_16x16x32_bf16(xa[i], xb[j], acc[i][j], 0, 0, 0);
        // load next even step
        if (kt + 2 < 64) {
#pragma unroll
            for (int i = 0; i < 4; ++i) {
                xa[i] = *(const bf16x8*)(pa[i] + 64);
                xb[i] = *(const bf16x8*)(pb[i] + 64);
            }
        }
#pragma unroll
        for (int i = 0; i < 4; ++i)
#pragma unroll
            for (int j = 0; j < 4; ++j)
                acc[i][j] = __builtin_amdgcn_mfma_f32_16x16x32_bf16(ya[i], yb[j], acc[i][j], 0, 0, 0);
#pragma unroll
        for (int i = 0; i < 4; ++i) { pa[i] += 64; pb[i] += 64; }
    }

    float* plane = C2P + (size_t)ks * NP2 * F;
    const int orow = (lane >> 4) * 4, ocol = lane & 15;
#pragma unroll
    for (int i = 0; i < 4; ++i)
#pragma unroll
        for (int j = 0; j < 4; ++j) {
            int gm = m0 + wm + i * 16 + orow;
            int gn = wn + j * 16 + ocol;
#pragma unroll
            for (int q = 0; q < 4; ++q)
                plane[(size_t)(gm + q) * F + gn] = acc[i][j][q];
        }
}

// ---------------- out = gelu(dvis[n] * sum_ks C2P[ks][n][f]) ----------------
__global__ void k_fin_out(const float* __restrict__ C2P, const float* __restrict__ Dv,
                          float* __restrict__ out) {
    int i4 = blockIdx.x * 256 + threadIdx.x;
    if (i4 < N * F / 4) {
        int n = i4 >> 5;
        float s = rsqrtf(fmaxf(Dv[n], 1.f));
        float4 v = make_float4(0.f, 0.f, 0.f, 0.f);
#pragma unroll
        for (int ks = 0; ks < KS_C; ++ks) {
            float4 p = reinterpret_cast<const float4*>(C2P + (size_t)ks * NP2 * F)[i4];
            v.x += p.x; v.y += p.y; v.z += p.z; v.w += p.w;
        }
        float4 o;
        o.x = gelu_erf(s * v.x);
        o.y = gelu_erf(s * v.y);
        o.z = gelu_erf(s * v.z);
        o.w = gelu_erf(s * v.w);
        reinterpret_cast<float4*>(out)[i4] = o;
    }
}

extern "C" void kernel_launch(void* const* d_in, const int* in_sizes, int n_in,
                              void* d_out, int out_size, void* d_ws, size_t ws_size,
                              hipStream_t stream) {
    const float* x     = (const float*)d_in[0];
    const float* H     = (const float*)d_in[1];
    const float* W     = (const float*)d_in[2];
    const float* lin_w = (const float*)d_in[3];
    const float* lin_b = (const float*)d_in[4];
    float* out = (float*)d_out;

    char* ws = (char*)d_ws;
    ushort* Hbs = (ushort*)ws;                                   // NP*E*2      = 335,544,320
    ushort* y   = (ushort*)(ws + 335544320);                     // NP*F*2      = 5,242,880
    ushort* yT  = (ushort*)(ws + 340787200);                     // F*NP*2      = 5,242,880
    float*  tB  = (float*) (ws + 346030080);                     // 8*E*F*4     = 33,554,432
    ushort* tsT = (ushort*)(ws + 379584512);                     // F*E*2       = 2,097,152
    float*  C2P = (float*) (ws + 381681664);                     // 4*NP2*F*4   = 41,156,608
    float*  DeP = (float*) (ws + 422838272);                     // 1024*E*4    = 33,554,432
    float*  Dv  = (float*) (ws + 456392704);                     // N*4         = 80,000
    float*  se  = (float*) (ws + 456472704);                     // E*4
    float*  lwT = (float*) (ws + 456505472);                     // F*F*4

    k_transpose_lw<<<64, 256, 0, stream>>>(lin_w, lwT);
    k_prep<<<NP / 20, 256, 0, stream>>>(H, Dv, DeP, Hbs);
    k_se<<<E / 64, 256, 0, stream>>>(DeP, W, se);
    k_xw<<<NP / 4, 128, 0, stream>>>(x, lwT, lin_b, Dv, y);
    k_ytrans<<<(NP / 64) * 2, 256, 0, stream>>>(y, yT);
    k_gemmB<<<64 * KS_B, 256, 0, stream>>>(Hbs, yT, tB);
    k_tst<<<(E / 64) * 2, 256, 0, stream>>>(tB, se, tsT);
    k_gemmC<<<157 * KS_C, 256, 0, stream>>>(Hbs, tsT, C2P);
    k_fin_out<<<(N * F / 4 + 255) / 256, 256, 0, stream>>>(C2P, Dv, out);
}

// Round 9
// 599.965 us; speedup vs baseline: 1.1063x; 1.1063x over previous
//
#include <hip/hip_runtime.h>
#include <math.h>

static constexpr int N = 20000;       // nodes
static constexpr int E = 8192;        // hyperedges
static constexpr int F = 128;         // feature dim
static constexpr int NP = 20480;      // padded node count (K for gemmB; 1024*20)
static constexpr int NP2 = 20096;     // padded node count for gemmC output planes (157*128)
static constexpr int PREP_BLOCKS = 1024;  // 20 rows each; blocks >= 1000 are pad
static constexpr int PREP_REAL = 1000;
static constexpr int XW_BLOCKS = NP / 8;  // 2560, 8 rows each
static constexpr int KS_B = 8;        // gemmB split-K
static constexpr int KS_C = 4;        // gemmC split-K

typedef short bf16x8 __attribute__((ext_vector_type(8)));
typedef float f32x4 __attribute__((ext_vector_type(4)));

__device__ __forceinline__ float gelu_erf(float x) {
    return 0.5f * x * (1.0f + erff(x * 0.70710678118654752440f));
}
__device__ __forceinline__ ushort f2bf(float f) {
    unsigned u = __float_as_uint(f);
    return (ushort)((u + 0x7FFFu + ((u >> 16) & 1u)) >> 16);
}

// ---------------- lwT[k][f] = lin_w[f][k] ----------------
__global__ void k_transpose_lw(const float* __restrict__ lin_w, float* __restrict__ lwT) {
    int idx = blockIdx.x * 256 + threadIdx.x;
    if (idx < F * F) {
        int k = idx >> 7, f = idx & 127;
        lwT[idx] = lin_w[f * F + k];
    }
}

// ---------------- fused: prep (blocks 0..1023) + xw->yT (blocks 1024..3583) ----------------
// prep: stream H -> DeP col-partials + Hbs = bf16(dvis[v]*H[v][e]); 20 rows/block.
// xw:   y = bf16(x@lw^T + b) for 8 rows, transposed in LDS, written straight to yT.
// The two groups co-schedule on the CUs: prep is HBM-bound, xw is VALU-bound.
__global__ __launch_bounds__(256) void k_prep_xw(const float* __restrict__ H,
                                                 float* __restrict__ DeP,
                                                 ushort* __restrict__ Hbs,
                                                 const float* __restrict__ x,
                                                 const float* __restrict__ lwT,
                                                 const float* __restrict__ lin_b,
                                                 ushort* __restrict__ yT) {
    __shared__ __align__(16) char smem[4096];
    const int tid = threadIdx.x;

    if (blockIdx.x < PREP_BLOCKS) {
        // ================= prep =================
        const int lane = tid & 63, wid = tid >> 6;
        const int r0 = blockIdx.x * 20;
        if (r0 >= N) {        // pad rows [N, NP): Hbs = 0
            uint4 z = make_uint4(0, 0, 0, 0);
            for (int r = 0; r < 20; ++r) {
                ushort* orow = Hbs + (size_t)(r0 + r) * E;
#pragma unroll
                for (int j = 0; j < 4; ++j) *(uint4*)(orow + (j * 256 + tid) * 8) = z;
            }
            return;
        }
        float (*rp)[4] = (float(*)[4])smem;    // [20][4]
        float4 ca[4][2];
#pragma unroll
        for (int j = 0; j < 4; ++j) {
            ca[j][0] = make_float4(0.f, 0.f, 0.f, 0.f);
            ca[j][1] = make_float4(0.f, 0.f, 0.f, 0.f);
        }
        for (int r = 0; r < 20; ++r) {
            const float* row = H + (size_t)(r0 + r) * E;
            float4 va[4], vb[4];
            float rs = 0.f;
#pragma unroll
            for (int j = 0; j < 4; ++j) {
                const float* base = row + (j * 256 + tid) * 8;   // 32B contiguous per thread
                va[j] = *(const float4*)(base);
                vb[j] = *(const float4*)(base + 4);
                ca[j][0].x += va[j].x; ca[j][0].y += va[j].y; ca[j][0].z += va[j].z; ca[j][0].w += va[j].w;
                ca[j][1].x += vb[j].x; ca[j][1].y += vb[j].y; ca[j][1].z += vb[j].z; ca[j][1].w += vb[j].w;
                rs += (va[j].x + va[j].y) + (va[j].z + va[j].w);
                rs += (vb[j].x + vb[j].y) + (vb[j].z + vb[j].w);
            }
#pragma unroll
            for (int off = 32; off > 0; off >>= 1) rs += __shfl_xor(rs, off, 64);
            if (lane == 0) rp[r][wid] = rs;
            __syncthreads();
            float scale = rsqrtf(fmaxf(rp[r][0] + rp[r][1] + rp[r][2] + rp[r][3], 1.f));
            ushort* orow = Hbs + (size_t)(r0 + r) * E;
#pragma unroll
            for (int j = 0; j < 4; ++j) {
                uint4 o;
                o.x = (unsigned)f2bf(va[j].x * scale) | ((unsigned)f2bf(va[j].y * scale) << 16);
                o.y = (unsigned)f2bf(va[j].z * scale) | ((unsigned)f2bf(va[j].w * scale) << 16);
                o.z = (unsigned)f2bf(vb[j].x * scale) | ((unsigned)f2bf(vb[j].y * scale) << 16);
                o.w = (unsigned)f2bf(vb[j].z * scale) | ((unsigned)f2bf(vb[j].w * scale) << 16);
                *(uint4*)(orow + (j * 256 + tid) * 8) = o;       // 16B contiguous store
            }
        }
        float* dp = DeP + (size_t)blockIdx.x * E;
#pragma unroll
        for (int j = 0; j < 4; ++j) {
            *(float4*)(dp + (j * 256 + tid) * 8) = ca[j][0];
            *(float4*)(dp + (j * 256 + tid) * 8 + 4) = ca[j][1];
        }
    } else {
        // ================= xw -> yT =================
        const int bxx = blockIdx.x - PREP_BLOCKS;
        const int r0 = bxx * 8;
        if (r0 >= N) {        // pad cols of yT
            if (tid < 128) {
                uint4 z = make_uint4(0, 0, 0, 0);
                *(uint4*)(yT + (size_t)tid * NP + r0) = z;
            }
            return;
        }
        float* xs = (float*)smem;              // [8][128] fp32
#pragma unroll
        for (int c = 0; c < 4; ++c) {
            int lin = c * 256 + tid;
            xs[lin] = x[(size_t)r0 * F + lin];
        }
        __syncthreads();
        const int f = tid & 127, half = tid >> 7;    // rows half*4 .. half*4+3
        float b = lin_b[f];
        float a0 = b, a1 = b, a2 = b, a3 = b;
        const float* xr = xs + (half * 4) * F;
#pragma unroll 4
        for (int k = 0; k < F; ++k) {
            float lw = lwT[k * F + f];
            a0 += xr[0 * F + k] * lw;
            a1 += xr[1 * F + k] * lw;
            a2 += xr[2 * F + k] * lw;
            a3 += xr[3 * F + k] * lw;
        }
        __syncthreads();                        // all xs reads done
        ushort* tile = (ushort*)smem;           // [8][128] bf16
        tile[(half * 4 + 0) * F + f] = f2bf(a0);
        tile[(half * 4 + 1) * F + f] = f2bf(a1);
        tile[(half * 4 + 2) * F + f] = f2bf(a2);
        tile[(half * 4 + 3) * F + f] = f2bf(a3);
        __syncthreads();
        if (tid < 128) {
            unsigned u[4];
#pragma unroll
            for (int qq = 0; qq < 4; ++qq) {
                ushort lo = tile[(qq * 2 + 0) * F + tid];
                ushort hi = tile[(qq * 2 + 1) * F + tid];
                u[qq] = (unsigned)lo | ((unsigned)hi << 16);
            }
            uint4 o = make_uint4(u[0], u[1], u[2], u[3]);
            *(uint4*)(yT + (size_t)tid * NP + r0) = o;
        }
    }
}

// ---------------- se[e] = W[e] / clip(sum_p DeP[p][e], 1) ----------------
__global__ void k_se(const float* __restrict__ DeP, const float* __restrict__ W,
                     float* __restrict__ se) {
    __shared__ float red[4][64];
    const int tid = threadIdx.x;
    const int c = blockIdx.x * 64 + (tid & 63);
    const int pg = tid >> 6;
    float s = 0.f;
    for (int p = pg; p < PREP_REAL; p += 4) s += DeP[(size_t)p * E + c];
    red[pg][tid & 63] = s;
    __syncthreads();
    if (tid < 64) {
        float d = red[0][tid] + red[1][tid] + red[2][tid] + red[3][tid];
        int e = blockIdx.x * 64 + tid;
        se[e] = W[e] / fmaxf(d, 1.f);
    }
}

// ---------------- tsT[f][e] = bf16(se[e] * sum_ks tB[ks][e][f])  (reduce + transpose) ------
__global__ void k_tst(const float* __restrict__ tB, const float* __restrict__ se,
                      ushort* __restrict__ tsT) {
    __shared__ __align__(16) char tl[8192];
    int tid = threadIdx.x;
    int r0 = (blockIdx.x >> 1) * 64;   // e
    int c0 = (blockIdx.x & 1) * 64;    // f
#pragma unroll
    for (int c = 0; c < 4; ++c) {
        int lin = c * 256 + tid;
        int row = lin >> 4, ch = lin & 15;
        size_t base = (size_t)(r0 + row) * F + c0 + ch * 4;
        float4 v = make_float4(0.f, 0.f, 0.f, 0.f);
#pragma unroll
        for (int ks = 0; ks < KS_B; ++ks) {
            float4 p = *(const float4*)(tB + (size_t)ks * E * F + base);
            v.x += p.x; v.y += p.y; v.z += p.z; v.w += p.w;
        }
        float s = se[r0 + row];
        ushort4 b;
        b.x = f2bf(v.x * s); b.y = f2bf(v.y * s); b.z = f2bf(v.z * s); b.w = f2bf(v.w * s);
        int key = ((row ^ (row >> 3)) & 7) << 4;
        *(ushort4*)(tl + row * 128 + ((ch * 8) ^ key)) = b;
    }
    __syncthreads();
#pragma unroll
    for (int c = 0; c < 2; ++c) {
        int lin = c * 256 + tid;
        int fl = lin >> 3, vch = lin & 7;
        unsigned u[4];
#pragma unroll
        for (int qq = 0; qq < 4; ++qq) {
            int r1 = vch * 8 + qq * 2, r2 = r1 + 1;
            ushort a = *(const ushort*)(tl + r1 * 128 + ((fl * 2) ^ (((r1 ^ (r1 >> 3)) & 7) << 4)));
            ushort b = *(const ushort*)(tl + r2 * 128 + ((fl * 2) ^ (((r2 ^ (r2 >> 3)) & 7) << 4)));
            u[qq] = (unsigned)a | ((unsigned)b << 16);
        }
        uint4 o = make_uint4(u[0], u[1], u[2], u[3]);
        *(uint4*)(tsT + (size_t)(c0 + fl) * E + r0 + vch * 8) = o;
    }
}

// ---------------- gemmB (MFMA): tB[ks][e][f] = sum_{v in chunk} Hbs[v][e] * yT[f][v] ------
// R6 structure: dbuf LDS, 1 barrier/step. XCD swizzle: each XCD owns one ks (B slice L2-hot).
__global__ __launch_bounds__(256) void k_gemmB(const ushort* __restrict__ Hbs,
                                               const ushort* __restrict__ yT,
                                               float* __restrict__ tB) {
    __shared__ __align__(16) char lA[2][16384];   // As[e 128][v 64] bf16, key ((e>>3)&7)<<4
    __shared__ __align__(16) char lB[2][16384];   // Bs[f 128][v 64] bf16, key (f&7)<<4
    const int tid = threadIdx.x;
    const int sw = (blockIdx.x & 7) * 64 + (blockIdx.x >> 3);   // bijective (512 % 8 == 0)
    const int m0 = (sw & 63) * 128;    // e tile
    const int ks = sw >> 6;
    const int k0 = ks * 2560;          // v chunk
    const int lane = tid & 63, w = tid >> 6;
    const int wm = (w & 1) * 64, wn = (w >> 1) * 64;
    const int lrow = lane & 15, g16 = (lane >> 4) * 16;
    const int NSTEP = 40;

    const int vq = tid >> 4;
    const int e8 = (tid & 15) * 8;
    const ushort* pa = Hbs + (size_t)(k0 + vq * 4) * E + m0 + e8;
    const int abase = e8 * 128 + ((vq * 8) ^ ((tid & 7) << 4));

    int bwoff[4];
    const uint4* pb[4];
#pragma unroll
    for (int c = 0; c < 4; ++c) {
        int lin = c * 256 + tid;
        int row = lin >> 3, ch = lin & 7;
        bwoff[c] = row * 128 + ((ch * 16) ^ ((row & 7) << 4));
        pb[c] = (const uint4*)(yT + (size_t)row * NP + k0 + ch * 8);
    }
    int aoff[4][2], boff[4][2];
#pragma unroll
    for (int f = 0; f < 4; ++f)
#pragma unroll
        for (int kk = 0; kk < 2; ++kk) {
            int ma = wm + f * 16 + lrow;
            aoff[f][kk] = ma * 128 + (((kk * 64) + g16) ^ (((ma >> 3) & 7) << 4));
            int nb = wn + f * 16 + lrow;
            boff[f][kk] = nb * 128 + (((kk * 64) + g16) ^ ((nb & 7) << 4));
        }

    f32x4 zero4 = {0.f, 0.f, 0.f, 0.f};
    f32x4 acc[4][4];
#pragma unroll
    for (int i = 0; i < 4; ++i)
#pragma unroll
        for (int j = 0; j < 4; ++j) acc[i][j] = zero4;

    uint4 ra[4], rb[4];
#pragma unroll
    for (int r = 0; r < 4; ++r) ra[r] = *(const uint4*)(pa + (size_t)r * E);
#pragma unroll
    for (int c = 0; c < 4; ++c) rb[c] = pb[c][0];
    {
        const ushort* u0 = (const ushort*)&ra[0];
        const ushort* u1 = (const ushort*)&ra[1];
        const ushort* u2 = (const ushort*)&ra[2];
        const ushort* u3 = (const ushort*)&ra[3];
#pragma unroll
        for (int i = 0; i < 8; ++i) {
            uint2 wv;
            wv.x = (unsigned)u0[i] | ((unsigned)u1[i] << 16);
            wv.y = (unsigned)u2[i] | ((unsigned)u3[i] << 16);
            *(uint2*)(lA[0] + abase + i * 128) = wv;
        }
#pragma unroll
        for (int c = 0; c < 4; ++c) *(uint4*)(lB[0] + bwoff[c]) = rb[c];
    }
    pa += (size_t)64 * E;
#pragma unroll
    for (int r = 0; r < 4; ++r) ra[r] = *(const uint4*)(pa + (size_t)r * E);
#pragma unroll
    for (int c = 0; c < 4; ++c) { pb[c] += 8; rb[c] = pb[c][0]; }
    __syncthreads();

    for (int kt = 0; kt < NSTEP; ++kt) {
        const int cur = kt & 1;
        if (kt + 1 < NSTEP) {
            const ushort* u0 = (const ushort*)&ra[0];
            const ushort* u1 = (const ushort*)&ra[1];
            const ushort* u2 = (const ushort*)&ra[2];
            const ushort* u3 = (const ushort*)&ra[3];
#pragma unroll
            for (int i = 0; i < 8; ++i) {
                uint2 wv;
                wv.x = (unsigned)u0[i] | ((unsigned)u1[i] << 16);
                wv.y = (unsigned)u2[i] | ((unsigned)u3[i] << 16);
                *(uint2*)(lA[cur ^ 1] + abase + i * 128) = wv;
            }
#pragma unroll
            for (int c = 0; c < 4; ++c) *(uint4*)(lB[cur ^ 1] + bwoff[c]) = rb[c];
        }
        if (kt + 2 < NSTEP) {
            pa += (size_t)64 * E;
#pragma unroll
            for (int r = 0; r < 4; ++r) ra[r] = *(const uint4*)(pa + (size_t)r * E);
#pragma unroll
            for (int c = 0; c < 4; ++c) { pb[c] += 8; rb[c] = pb[c][0]; }
        }
#pragma unroll
        for (int kk = 0; kk < 2; ++kk) {
            bf16x8 av[4], bv[4];
#pragma unroll
            for (int f = 0; f < 4; ++f) av[f] = *(const bf16x8*)(lA[cur] + aoff[f][kk]);
#pragma unroll
            for (int f = 0; f < 4; ++f) bv[f] = *(const bf16x8*)(lB[cur] + boff[f][kk]);
#pragma unroll
            for (int i = 0; i < 4; ++i)
#pragma unroll
                for (int j = 0; j < 4; ++j)
                    acc[i][j] = __builtin_amdgcn_mfma_f32_16x16x32_bf16(av[i], bv[j], acc[i][j], 0, 0, 0);
        }
        if (kt + 1 < NSTEP) __syncthreads();
    }
    float* plane = tB + (size_t)ks * E * F;
    const int orow = (lane >> 4) * 4, ocol = lane & 15;
#pragma unroll
    for (int i = 0; i < 4; ++i)
#pragma unroll
        for (int j = 0; j < 4; ++j) {
            int gm = m0 + wm + i * 16 + orow;
            int gn = wn + j * 16 + ocol;
#pragma unroll
            for (int q = 0; q < 4; ++q)
                plane[(size_t)(gm + q) * F + gn] = acc[i][j][q];
        }
}

// ---------------- gemmC (MFMA): C2P[ks][n][f] = sum_{e in chunk} Hbs[n][e] * tsT[f][e] -----
// R6 structure: dbuf LDS, 1 barrier/step. Bijective XCD swizzle (628 % 8 != 0 -> m204 form).
__global__ __launch_bounds__(256) void k_gemmC(const ushort* __restrict__ Hbs,
                                               const ushort* __restrict__ tsT,
                                               float* __restrict__ C2P) {
    __shared__ __align__(16) char lA[2][16384];
    __shared__ __align__(16) char lB[2][16384];
    const int tid = threadIdx.x;
    const int qq_ = 78, rr_ = 4;                     // 628 = 8*78 + 4
    const int xcd = blockIdx.x & 7, idx = blockIdx.x >> 3;
    const int sw = (xcd < rr_ ? xcd * (qq_ + 1) : rr_ * (qq_ + 1) + (xcd - rr_) * qq_) + idx;
    const int m0 = (sw % 157) * 128;
    const int ks = sw / 157;
    const int k0 = ks * 2048;
    const int lane = tid & 63, w = tid >> 6;
    const int wm = (w & 1) * 64, wn = (w >> 1) * 64;
    const int lrow = lane & 15, g16 = (lane >> 4) * 16;
    const int NSTEP = 32;

    int awoff[4], bwoff[4];
    const uint4* pA[4];
    const uint4* pB[4];
#pragma unroll
    for (int c = 0; c < 4; ++c) {
        int lin = c * 256 + tid;
        int row = lin >> 3, ch = lin & 7;
        awoff[c] = row * 128 + ((ch * 16) ^ ((row & 7) << 4));
        bwoff[c] = awoff[c];
        pA[c] = (const uint4*)(Hbs + (size_t)(m0 + row) * E + k0 + ch * 8);
        pB[c] = (const uint4*)(tsT + (size_t)row * E + k0 + ch * 8);
    }
    int aoff[4][2], boff[4][2];
#pragma unroll
    for (int f = 0; f < 4; ++f)
#pragma unroll
        for (int kk = 0; kk < 2; ++kk) {
            int ma = wm + f * 16 + lrow;
            aoff[f][kk] = ma * 128 + (((kk * 64) + g16) ^ ((ma & 7) << 4));
            int nb = wn + f * 16 + lrow;
            boff[f][kk] = nb * 128 + (((kk * 64) + g16) ^ ((nb & 7) << 4));
        }

    f32x4 zero4 = {0.f, 0.f, 0.f, 0.f};
    f32x4 acc[4][4];
#pragma unroll
    for (int i = 0; i < 4; ++i)
#pragma unroll
        for (int j = 0; j < 4; ++j) acc[i][j] = zero4;

    uint4 ra[4], rb[4];
#pragma unroll
    for (int c = 0; c < 4; ++c) { ra[c] = pA[c][0]; rb[c] = pB[c][0]; }
#pragma unroll
    for (int c = 0; c < 4; ++c) {
        *(uint4*)(lA[0] + awoff[c]) = ra[c];
        *(uint4*)(lB[0] + bwoff[c]) = rb[c];
    }
#pragma unroll
    for (int c = 0; c < 4; ++c) {
        pA[c] += 8; pB[c] += 8;
        ra[c] = pA[c][0]; rb[c] = pB[c][0];
    }
    __syncthreads();

    for (int kt = 0; kt < NSTEP; ++kt) {
        const int cur = kt & 1;
        if (kt + 1 < NSTEP) {
#pragma unroll
            for (int c = 0; c < 4; ++c) {
                *(uint4*)(lA[cur ^ 1] + awoff[c]) = ra[c];
                *(uint4*)(lB[cur ^ 1] + bwoff[c]) = rb[c];
            }
        }
        if (kt + 2 < NSTEP) {
#pragma unroll
            for (int c = 0; c < 4; ++c) {
                pA[c] += 8; pB[c] += 8;
                ra[c] = pA[c][0]; rb[c] = pB[c][0];
            }
        }
#pragma unroll
        for (int kk = 0; kk < 2; ++kk) {
            bf16x8 av[4], bv[4];
#pragma unroll
            for (int f = 0; f < 4; ++f) av[f] = *(const bf16x8*)(lA[cur] + aoff[f][kk]);
#pragma unroll
            for (int f = 0; f < 4; ++f) bv[f] = *(const bf16x8*)(lB[cur] + boff[f][kk]);
#pragma unroll
            for (int i = 0; i < 4; ++i)
#pragma unroll
                for (int j = 0; j < 4; ++j)
                    acc[i][j] = __builtin_amdgcn_mfma_f32_16x16x32_bf16(av[i], bv[j], acc[i][j], 0, 0, 0);
        }
        if (kt + 1 < NSTEP) __syncthreads();
    }
    float* plane = C2P + (size_t)ks * NP2 * F;
    const int orow = (lane >> 4) * 4, ocol = lane & 15;
#pragma unroll
    for (int i = 0; i < 4; ++i)
#pragma unroll
        for (int j = 0; j < 4; ++j) {
            int gm = m0 + wm + i * 16 + orow;
            int gn = wn + j * 16 + ocol;
#pragma unroll
            for (int q = 0; q < 4; ++q)
                plane[(size_t)(gm + q) * F + gn] = acc[i][j][q];
        }
}

// ---------------- out = gelu(sum_ks C2P[ks][n][f])   (dvis folded into Hbs) ----------------
__global__ void k_fin_out(const float* __restrict__ C2P, float* __restrict__ out) {
    int i4 = blockIdx.x * 256 + threadIdx.x;
    if (i4 < N * F / 4) {
        float4 v = make_float4(0.f, 0.f, 0.f, 0.f);
#pragma unroll
        for (int ks = 0; ks < KS_C; ++ks) {
            float4 p = reinterpret_cast<const float4*>(C2P + (size_t)ks * NP2 * F)[i4];
            v.x += p.x; v.y += p.y; v.z += p.z; v.w += p.w;
        }
        float4 o;
        o.x = gelu_erf(v.x);
        o.y = gelu_erf(v.y);
        o.z = gelu_erf(v.z);
        o.w = gelu_erf(v.w);
        reinterpret_cast<float4*>(out)[i4] = o;
    }
}

extern "C" void kernel_launch(void* const* d_in, const int* in_sizes, int n_in,
                              void* d_out, int out_size, void* d_ws, size_t ws_size,
                              hipStream_t stream) {
    const float* x     = (const float*)d_in[0];
    const float* H     = (const float*)d_in[1];
    const float* W     = (const float*)d_in[2];
    const float* lin_w = (const float*)d_in[3];
    const float* lin_b = (const float*)d_in[4];
    float* out = (float*)d_out;

    // workspace layout (bytes): ~451 MiB
    char* ws = (char*)d_ws;
    ushort* Hbs = (ushort*)ws;                                   // NP*E*2      = 335,544,320
    ushort* yT  = (ushort*)(ws + 335544320);                     // F*NP*2      = 5,242,880
    float*  tB  = (float*) (ws + 340787200);                     // 8*E*F*4     = 33,554,432
    ushort* tsT = (ushort*)(ws + 374341632);                     // F*E*2       = 2,097,152
    float*  C2P = (float*) (ws + 376438784);                     // 4*NP2*F*4   = 41,156,608
    float*  DeP = (float*) (ws + 417595392);                     // 1024*E*4    = 33,554,432
    float*  se  = (float*) (ws + 451149824);                     // E*4
    float*  lwT = (float*) (ws + 451182592);                     // F*F*4

    k_transpose_lw<<<64, 256, 0, stream>>>(lin_w, lwT);
    k_prep_xw<<<PREP_BLOCKS + XW_BLOCKS, 256, 0, stream>>>(H, DeP, Hbs, x, lwT, lin_b, yT);
    k_se<<<E / 64, 256, 0, stream>>>(DeP, W, se);
    k_gemmB<<<64 * KS_B, 256, 0, stream>>>(Hbs, yT, tB);
    k_tst<<<(E / 64) * 2, 256, 0, stream>>>(tB, se, tsT);
    k_gemmC<<<157 * KS_C, 256, 0, stream>>>(Hbs, tsT, C2P);
    k_fin_out<<<(N * F / 4 + 255) / 256, 256, 0, stream>>>(C2P, out);
}

// Round 10
// 509.972 us; speedup vs baseline: 1.3015x; 1.1765x over previous
//
#include <hip/hip_runtime.h>
#include <math.h>

static constexpr int N = 20000;       // nodes
static constexpr int E = 8192;        // hyperedges
static constexpr int F = 128;         // feature dim
static constexpr int NP = 20480;      // padded node count (K for gemmB; 1024*20)
static constexpr int NP2 = 20096;     // padded node count for gemmC output planes (157*128)
static constexpr int PREP_BLOCKS = 1024;  // 20 rows each; blocks >= 1000 are pad
static constexpr int PREP_REAL = 1000;
static constexpr int XW_BLOCKS = NP / 8;  // 2560, 8 rows each
static constexpr int KS_B = 8;        // gemmB split-K
static constexpr int KS_C = 4;        // gemmC split-K

typedef short bf16x8 __attribute__((ext_vector_type(8)));
typedef float f32x4 __attribute__((ext_vector_type(4)));

__device__ __forceinline__ float gelu_erf(float x) {
    return 0.5f * x * (1.0f + erff(x * 0.70710678118654752440f));
}
__device__ __forceinline__ ushort f2bf(float f) {
    unsigned u = __float_as_uint(f);
    return (ushort)((u + 0x7FFFu + ((u >> 16) & 1u)) >> 16);
}
// async global->LDS, 16B per lane (global source per-lane, LDS dest = base + lane*16)
__device__ __forceinline__ void gload16(const void* g, void* lds) {
    __builtin_amdgcn_global_load_lds(
        (const __attribute__((address_space(1))) unsigned int*)g,
        (__attribute__((address_space(3))) unsigned int*)lds, 16, 0, 0);
}

// ---------------- lwT[k][f] = lin_w[f][k] ----------------
__global__ void k_transpose_lw(const float* __restrict__ lin_w, float* __restrict__ lwT) {
    int idx = blockIdx.x * 256 + threadIdx.x;
    if (idx < F * F) {
        int k = idx >> 7, f = idx & 127;
        lwT[idx] = lin_w[f * F + k];
    }
}

// ---------------- fused: prep (blocks 0..1023) + xw->yT (blocks 1024..3583) ----------------
__global__ __launch_bounds__(256) void k_prep_xw(const float* __restrict__ H,
                                                 float* __restrict__ DeP,
                                                 ushort* __restrict__ Hbs,
                                                 const float* __restrict__ x,
                                                 const float* __restrict__ lwT,
                                                 const float* __restrict__ lin_b,
                                                 ushort* __restrict__ yT) {
    __shared__ __align__(16) char smem[4096];
    const int tid = threadIdx.x;

    if (blockIdx.x < PREP_BLOCKS) {
        // ================= prep =================
        const int lane = tid & 63, wid = tid >> 6;
        const int r0 = blockIdx.x * 20;
        if (r0 >= N) {        // pad rows [N, NP): Hbs = 0
            uint4 z = make_uint4(0, 0, 0, 0);
            for (int r = 0; r < 20; ++r) {
                ushort* orow = Hbs + (size_t)(r0 + r) * E;
#pragma unroll
                for (int j = 0; j < 4; ++j) *(uint4*)(orow + (j * 256 + tid) * 8) = z;
            }
            return;
        }
        float (*rp)[4] = (float(*)[4])smem;    // [20][4]
        float4 ca[4][2];
#pragma unroll
        for (int j = 0; j < 4; ++j) {
            ca[j][0] = make_float4(0.f, 0.f, 0.f, 0.f);
            ca[j][1] = make_float4(0.f, 0.f, 0.f, 0.f);
        }
        for (int r = 0; r < 20; ++r) {
            const float* row = H + (size_t)(r0 + r) * E;
            float4 va[4], vb[4];
            float rs = 0.f;
#pragma unroll
            for (int j = 0; j < 4; ++j) {
                const float* base = row + (j * 256 + tid) * 8;   // 32B contiguous per thread
                va[j] = *(const float4*)(base);
                vb[j] = *(const float4*)(base + 4);
                ca[j][0].x += va[j].x; ca[j][0].y += va[j].y; ca[j][0].z += va[j].z; ca[j][0].w += va[j].w;
                ca[j][1].x += vb[j].x; ca[j][1].y += vb[j].y; ca[j][1].z += vb[j].z; ca[j][1].w += vb[j].w;
                rs += (va[j].x + va[j].y) + (va[j].z + va[j].w);
                rs += (vb[j].x + vb[j].y) + (vb[j].z + vb[j].w);
            }
#pragma unroll
            for (int off = 32; off > 0; off >>= 1) rs += __shfl_xor(rs, off, 64);
            if (lane == 0) rp[r][wid] = rs;
            __syncthreads();
            float scale = rsqrtf(fmaxf(rp[r][0] + rp[r][1] + rp[r][2] + rp[r][3], 1.f));
            ushort* orow = Hbs + (size_t)(r0 + r) * E;
#pragma unroll
            for (int j = 0; j < 4; ++j) {
                uint4 o;
                o.x = (unsigned)f2bf(va[j].x * scale) | ((unsigned)f2bf(va[j].y * scale) << 16);
                o.y = (unsigned)f2bf(va[j].z * scale) | ((unsigned)f2bf(va[j].w * scale) << 16);
                o.z = (unsigned)f2bf(vb[j].x * scale) | ((unsigned)f2bf(vb[j].y * scale) << 16);
                o.w = (unsigned)f2bf(vb[j].z * scale) | ((unsigned)f2bf(vb[j].w * scale) << 16);
                *(uint4*)(orow + (j * 256 + tid) * 8) = o;       // 16B contiguous store
            }
        }
        float* dp = DeP + (size_t)blockIdx.x * E;
#pragma unroll
        for (int j = 0; j < 4; ++j) {
            *(float4*)(dp + (j * 256 + tid) * 8) = ca[j][0];
            *(float4*)(dp + (j * 256 + tid) * 8 + 4) = ca[j][1];
        }
    } else {
        // ================= xw -> yT =================
        const int bxx = blockIdx.x - PREP_BLOCKS;
        const int r0 = bxx * 8;
        if (r0 >= N) {        // pad cols of yT
            if (tid < 128) {
                uint4 z = make_uint4(0, 0, 0, 0);
                *(uint4*)(yT + (size_t)tid * NP + r0) = z;
            }
            return;
        }
        float* xs = (float*)smem;              // [8][128] fp32
#pragma unroll
        for (int c = 0; c < 4; ++c) {
            int lin = c * 256 + tid;
            xs[lin] = x[(size_t)r0 * F + lin];
        }
        __syncthreads();
        const int f = tid & 127, half = tid >> 7;    // rows half*4 .. half*4+3
        float b = lin_b[f];
        float a0 = b, a1 = b, a2 = b, a3 = b;
        const float* xr = xs + (half * 4) * F;
#pragma unroll 4
        for (int k = 0; k < F; ++k) {
            float lw = lwT[k * F + f];
            a0 += xr[0 * F + k] * lw;
            a1 += xr[1 * F + k] * lw;
            a2 += xr[2 * F + k] * lw;
            a3 += xr[3 * F + k] * lw;
        }
        __syncthreads();                        // all xs reads done
        ushort* tile = (ushort*)smem;           // [8][128] bf16
        tile[(half * 4 + 0) * F + f] = f2bf(a0);
        tile[(half * 4 + 1) * F + f] = f2bf(a1);
        tile[(half * 4 + 2) * F + f] = f2bf(a2);
        tile[(half * 4 + 3) * F + f] = f2bf(a3);
        __syncthreads();
        if (tid < 128) {
            unsigned u[4];
#pragma unroll
            for (int qq = 0; qq < 4; ++qq) {
                ushort lo = tile[(qq * 2 + 0) * F + tid];
                ushort hi = tile[(qq * 2 + 1) * F + tid];
                u[qq] = (unsigned)lo | ((unsigned)hi << 16);
            }
            uint4 o = make_uint4(u[0], u[1], u[2], u[3]);
            *(uint4*)(yT + (size_t)tid * NP + r0) = o;
        }
    }
}

// ---------------- se[e] = W[e] / clip(sum_p DeP[p][e], 1) ----------------
__global__ void k_se(const float* __restrict__ DeP, const float* __restrict__ W,
                     float* __restrict__ se) {
    __shared__ float red[4][64];
    const int tid = threadIdx.x;
    const int c = blockIdx.x * 64 + (tid & 63);
    const int pg = tid >> 6;
    float s = 0.f;
    for (int p = pg; p < PREP_REAL; p += 4) s += DeP[(size_t)p * E + c];
    red[pg][tid & 63] = s;
    __syncthreads();
    if (tid < 64) {
        float d = red[0][tid] + red[1][tid] + red[2][tid] + red[3][tid];
        int e = blockIdx.x * 64 + tid;
        se[e] = W[e] / fmaxf(d, 1.f);
    }
}

// ---------------- tsT[f][e] = bf16(se[e] * sum_ks tB[ks][e][f])  (reduce + transpose) ------
__global__ void k_tst(const float* __restrict__ tB, const float* __restrict__ se,
                      ushort* __restrict__ tsT) {
    __shared__ __align__(16) char tl[8192];
    int tid = threadIdx.x;
    int r0 = (blockIdx.x >> 1) * 64;   // e
    int c0 = (blockIdx.x & 1) * 64;    // f
#pragma unroll
    for (int c = 0; c < 4; ++c) {
        int lin = c * 256 + tid;
        int row = lin >> 4, ch = lin & 15;
        size_t base = (size_t)(r0 + row) * F + c0 + ch * 4;
        float4 v = make_float4(0.f, 0.f, 0.f, 0.f);
#pragma unroll
        for (int ks = 0; ks < KS_B; ++ks) {
            float4 p = *(const float4*)(tB + (size_t)ks * E * F + base);
            v.x += p.x; v.y += p.y; v.z += p.z; v.w += p.w;
        }
        float s = se[r0 + row];
        ushort4 b;
        b.x = f2bf(v.x * s); b.y = f2bf(v.y * s); b.z = f2bf(v.z * s); b.w = f2bf(v.w * s);
        int key = ((row ^ (row >> 3)) & 7) << 4;
        *(ushort4*)(tl + row * 128 + ((ch * 8) ^ key)) = b;
    }
    __syncthreads();
#pragma unroll
    for (int c = 0; c < 2; ++c) {
        int lin = c * 256 + tid;
        int fl = lin >> 3, vch = lin & 7;
        unsigned u[4];
#pragma unroll
        for (int qq = 0; qq < 4; ++qq) {
            int r1 = vch * 8 + qq * 2, r2 = r1 + 1;
            ushort a = *(const ushort*)(tl + r1 * 128 + ((fl * 2) ^ (((r1 ^ (r1 >> 3)) & 7) << 4)));
            ushort b = *(const ushort*)(tl + r2 * 128 + ((fl * 2) ^ (((r2 ^ (r2 >> 3)) & 7) << 4)));
            u[qq] = (unsigned)a | ((unsigned)b << 16);
        }
        uint4 o = make_uint4(u[0], u[1], u[2], u[3]);
        *(uint4*)(tsT + (size_t)(c0 + fl) * E + r0 + vch * 8) = o;
    }
}

// ---------------- gemmB (MFMA): tB[ks][e][f] = sum_{v in chunk} Hbs[v][e] * yT[f][v] ------
// A: reg-transpose staged (dbuf). B: global_load_lds width=16 (linear dest, inverse-swz src).
__global__ __launch_bounds__(256) void k_gemmB(const ushort* __restrict__ Hbs,
                                               const ushort* __restrict__ yT,
                                               float* __restrict__ tB) {
    __shared__ __align__(16) char lA[2][16384];   // As[e 128][v 64] bf16, key ((e>>3)&7)<<4
    __shared__ __align__(16) char lB[2][16384];   // Bs[f 128][v 64] bf16, key (f&7)<<4
    const int tid = threadIdx.x;
    const int sw = (blockIdx.x & 7) * 64 + (blockIdx.x >> 3);   // bijective (512 % 8 == 0)
    const int m0 = (sw & 63) * 128;    // e tile
    const int ks = sw >> 6;
    const int k0 = ks * 2560;          // v chunk
    const int lane = tid & 63, w = tid >> 6;
    const int wm = (w & 1) * 64, wn = (w >> 1) * 64;
    const int lrow = lane & 15, g16 = (lane >> 4) * 16;
    const int NSTEP = 40;

    const int vq = tid >> 4;
    const int e8 = (tid & 15) * 8;
    const ushort* pa = Hbs + (size_t)(k0 + vq * 4) * E + m0 + e8;
    const int abase = e8 * 128 + ((vq * 8) ^ ((tid & 7) << 4));

    // B staging via global_load_lds: wave w stages f-rows [w*32, w*32+32)
    const int row8 = lane >> 3, ch8 = lane & 7;
    const ushort* gB = yT + (size_t)(w * 32 + row8) * NP + k0 + ((ch8 ^ row8) * 8);
    const int ldstB = w * 32 * 128;

    int aoff[4][2], boff[4][2];
#pragma unroll
    for (int f = 0; f < 4; ++f)
#pragma unroll
        for (int kk = 0; kk < 2; ++kk) {
            int ma = wm + f * 16 + lrow;
            aoff[f][kk] = ma * 128 + (((kk * 64) + g16) ^ (((ma >> 3) & 7) << 4));
            int nb = wn + f * 16 + lrow;
            boff[f][kk] = nb * 128 + (((kk * 64) + g16) ^ ((nb & 7) << 4));
        }

    f32x4 zero4 = {0.f, 0.f, 0.f, 0.f};
    f32x4 acc[4][4];
#pragma unroll
    for (int i = 0; i < 4; ++i)
#pragma unroll
        for (int j = 0; j < 4; ++j) acc[i][j] = zero4;

    uint4 ra[4];
    // prologue: A tile0 regs->buf0; B tile0 gload->buf0; prefetch A tile1 regs.
#pragma unroll
    for (int r = 0; r < 4; ++r) ra[r] = *(const uint4*)(pa + (size_t)r * E);
    {
        const ushort* u0 = (const ushort*)&ra[0];
        const ushort* u1 = (const ushort*)&ra[1];
        const ushort* u2 = (const ushort*)&ra[2];
        const ushort* u3 = (const ushort*)&ra[3];
#pragma unroll
        for (int i = 0; i < 8; ++i) {
            uint2 wv;
            wv.x = (unsigned)u0[i] | ((unsigned)u1[i] << 16);
            wv.y = (unsigned)u2[i] | ((unsigned)u3[i] << 16);
            *(uint2*)(lA[0] + abase + i * 128) = wv;
        }
#pragma unroll
        for (int i = 0; i < 4; ++i)
            gload16(gB + (size_t)i * 8 * NP, lB[0] + ldstB + i * 1024);
    }
    pa += (size_t)64 * E;
#pragma unroll
    for (int r = 0; r < 4; ++r) ra[r] = *(const uint4*)(pa + (size_t)r * E);
    __syncthreads();

    for (int kt = 0; kt < NSTEP; ++kt) {
        const int cur = kt & 1;
        if (kt + 1 < NSTEP) {
            const ushort* u0 = (const ushort*)&ra[0];
            const ushort* u1 = (const ushort*)&ra[1];
            const ushort* u2 = (const ushort*)&ra[2];
            const ushort* u3 = (const ushort*)&ra[3];
#pragma unroll
            for (int i = 0; i < 8; ++i) {
                uint2 wv;
                wv.x = (unsigned)u0[i] | ((unsigned)u1[i] << 16);
                wv.y = (unsigned)u2[i] | ((unsigned)u3[i] << 16);
                *(uint2*)(lA[cur ^ 1] + abase + i * 128) = wv;
            }
            const int koff = (kt + 1) * 64;
#pragma unroll
            for (int i = 0; i < 4; ++i)
                gload16(gB + (size_t)i * 8 * NP + koff, lB[cur ^ 1] + ldstB + i * 1024);
        }
        if (kt + 2 < NSTEP) {
            pa += (size_t)64 * E;
#pragma unroll
            for (int r = 0; r < 4; ++r) ra[r] = *(const uint4*)(pa + (size_t)r * E);
        }
#pragma unroll
        for (int kk = 0; kk < 2; ++kk) {
            bf16x8 av[4], bv[4];
#pragma unroll
            for (int f = 0; f < 4; ++f) av[f] = *(const bf16x8*)(lA[cur] + aoff[f][kk]);
#pragma unroll
            for (int f = 0; f < 4; ++f) bv[f] = *(const bf16x8*)(lB[cur] + boff[f][kk]);
#pragma unroll
            for (int i = 0; i < 4; ++i)
#pragma unroll
                for (int j = 0; j < 4; ++j)
                    acc[i][j] = __builtin_amdgcn_mfma_f32_16x16x32_bf16(av[i], bv[j], acc[i][j], 0, 0, 0);
        }
        if (kt + 1 < NSTEP) __syncthreads();
    }
    float* plane = tB + (size_t)ks * E * F;
    const int orow = (lane >> 4) * 4, ocol = lane & 15;
#pragma unroll
    for (int i = 0; i < 4; ++i)
#pragma unroll
        for (int j = 0; j < 4; ++j) {
            int gm = m0 + wm + i * 16 + orow;
            int gn = wn + j * 16 + ocol;
#pragma unroll
            for (int q = 0; q < 4; ++q)
                plane[(size_t)(gm + q) * F + gn] = acc[i][j][q];
        }
}

// ---------------- gemmC (MFMA): C2P[ks][n][f] = sum_{e in chunk} Hbs[n][e] * tsT[f][e] -----
// BOTH operands staged via global_load_lds width=16 (linear dest, inverse-swz source,
// unchanged swizzled ds_read). Dbuf, 1 barrier/step. Bijective XCD swizzle.
__global__ __launch_bounds__(256) void k_gemmC(const ushort* __restrict__ Hbs,
                                               const ushort* __restrict__ tsT,
                                               float* __restrict__ C2P) {
    __shared__ __align__(16) char lA[2][16384];
    __shared__ __align__(16) char lB[2][16384];
    const int tid = threadIdx.x;
    const int qq_ = 78, rr_ = 4;                     // 628 = 8*78 + 4
    const int xcd = blockIdx.x & 7, idx = blockIdx.x >> 3;
    const int sw = (xcd < rr_ ? xcd * (qq_ + 1) : rr_ * (qq_ + 1) + (xcd - rr_) * qq_) + idx;
    const int m0 = (sw % 157) * 128;
    const int ks = sw / 157;
    const int k0 = ks * 2048;
    const int lane = tid & 63, w = tid >> 6;
    const int wm = (w & 1) * 64, wn = (w >> 1) * 64;
    const int lrow = lane & 15, g16 = (lane >> 4) * 16;
    const int NSTEP = 32;

    // gload staging: wave w stages rows [w*32, w*32+32) of both tiles
    const int row8 = lane >> 3, ch8 = lane & 7;
    const ushort* gA = Hbs + (size_t)(m0 + w * 32 + row8) * E + k0 + ((ch8 ^ row8) * 8);
    const ushort* gB = tsT + (size_t)(w * 32 + row8) * E + k0 + ((ch8 ^ row8) * 8);
    const int ldst = w * 32 * 128;

    int aoff[4][2], boff[4][2];
#pragma unroll
    for (int f = 0; f < 4; ++f)
#pragma unroll
        for (int kk = 0; kk < 2; ++kk) {
            int ma = wm + f * 16 + lrow;
            aoff[f][kk] = ma * 128 + (((kk * 64) + g16) ^ ((ma & 7) << 4));
            int nb = wn + f * 16 + lrow;
            boff[f][kk] = nb * 128 + (((kk * 64) + g16) ^ ((nb & 7) << 4));
        }

    f32x4 zero4 = {0.f, 0.f, 0.f, 0.f};
    f32x4 acc[4][4];
#pragma unroll
    for (int i = 0; i < 4; ++i)
#pragma unroll
        for (int j = 0; j < 4; ++j) acc[i][j] = zero4;

    // prologue: stage tile 0 into buf0
#pragma unroll
    for (int i = 0; i < 4; ++i) {
        gload16(gA + (size_t)i * 8 * E, lA[0] + ldst + i * 1024);
        gload16(gB + (size_t)i * 8 * E, lB[0] + ldst + i * 1024);
    }
    __syncthreads();

    for (int kt = 0; kt < NSTEP; ++kt) {
        const int cur = kt & 1;
        if (kt + 1 < NSTEP) {
            const int koff = (kt + 1) * 64;
#pragma unroll
            for (int i = 0; i < 4; ++i) {
                gload16(gA + (size_t)i * 8 * E + koff, lA[cur ^ 1] + ldst + i * 1024);
                gload16(gB + (size_t)i * 8 * E + koff, lB[cur ^ 1] + ldst + i * 1024);
            }
        }
#pragma unroll
        for (int kk = 0; kk < 2; ++kk) {
            bf16x8 av[4], bv[4];
#pragma unroll
            for (int f = 0; f < 4; ++f) av[f] = *(const bf16x8*)(lA[cur] + aoff[f][kk]);
#pragma unroll
            for (int f = 0; f < 4; ++f) bv[f] = *(const bf16x8*)(lB[cur] + boff[f][kk]);
#pragma unroll
            for (int i = 0; i < 4; ++i)
#pragma unroll
                for (int j = 0; j < 4; ++j)
                    acc[i][j] = __builtin_amdgcn_mfma_f32_16x16x32_bf16(av[i], bv[j], acc[i][j], 0, 0, 0);
        }
        if (kt + 1 < NSTEP) __syncthreads();
    }
    float* plane = C2P + (size_t)ks * NP2 * F;
    const int orow = (lane >> 4) * 4, ocol = lane & 15;
#pragma unroll
    for (int i = 0; i < 4; ++i)
#pragma unroll
        for (int j = 0; j < 4; ++j) {
            int gm = m0 + wm + i * 16 + orow;
            int gn = wn + j * 16 + ocol;
#pragma unroll
            for (int q = 0; q < 4; ++q)
                plane[(size_t)(gm + q) * F + gn] = acc[i][j][q];
        }
}

// ---------------- out = gelu(sum_ks C2P[ks][n][f])   (dvis folded into Hbs) ----------------
__global__ void k_fin_out(const float* __restrict__ C2P, float* __restrict__ out) {
    int i4 = blockIdx.x * 256 + threadIdx.x;
    if (i4 < N * F / 4) {
        float4 v = make_float4(0.f, 0.f, 0.f, 0.f);
#pragma unroll
        for (int ks = 0; ks < KS_C; ++ks) {
            float4 p = reinterpret_cast<const float4*>(C2P + (size_t)ks * NP2 * F)[i4];
            v.x += p.x; v.y += p.y; v.z += p.z; v.w += p.w;
        }
        float4 o;
        o.x = gelu_erf(v.x);
        o.y = gelu_erf(v.y);
        o.z = gelu_erf(v.z);
        o.w = gelu_erf(v.w);
        reinterpret_cast<float4*>(out)[i4] = o;
    }
}

extern "C" void kernel_launch(void* const* d_in, const int* in_sizes, int n_in,
                              void* d_out, int out_size, void* d_ws, size_t ws_size,
                              hipStream_t stream) {
    const float* x     = (const float*)d_in[0];
    const float* H     = (const float*)d_in[1];
    const float* W     = (const float*)d_in[2];
    const float* lin_w = (const float*)d_in[3];
    const float* lin_b = (const float*)d_in[4];
    float* out = (float*)d_out;

    // workspace layout (bytes): ~451 MiB
    char* ws = (char*)d_ws;
    ushort* Hbs = (ushort*)ws;                                   // NP*E*2      = 335,544,320
    ushort* yT  = (ushort*)(ws + 335544320);                     // F*NP*2      = 5,242,880
    float*  tB  = (float*) (ws + 340787200);                     // 8*E*F*4     = 33,554,432
    ushort* tsT = (ushort*)(ws + 374341632);                     // F*E*2       = 2,097,152
    float*  C2P = (float*) (ws + 376438784);                     // 4*NP2*F*4   = 41,156,608
    float*  DeP = (float*) (ws + 417595392);                     // 1024*E*4    = 33,554,432
    float*  se  = (float*) (ws + 451149824);                     // E*4
    float*  lwT = (float*) (ws + 451182592);                     // F*F*4

    k_transpose_lw<<<64, 256, 0, stream>>>(lin_w, lwT);
    k_prep_xw<<<PREP_BLOCKS + XW_BLOCKS, 256, 0, stream>>>(H, DeP, Hbs, x, lwT, lin_b, yT);
    k_se<<<E / 64, 256, 0, stream>>>(DeP, W, se);
    k_gemmB<<<64 * KS_B, 256, 0, stream>>>(Hbs, yT, tB);
    k_tst<<<(E / 64) * 2, 256, 0, stream>>>(tB, se, tsT);
    k_gemmC<<<157 * KS_C, 256, 0, stream>>>(Hbs, tsT, C2P);
    k_fin_out<<<(N * F / 4 + 255) / 256, 256, 0, stream>>>(C2P, out);
}

// Round 11
// 461.704 us; speedup vs baseline: 1.4376x; 1.1045x over previous
//
#include <hip/hip_runtime.h>
#include <math.h>

static constexpr int N = 20000;       // nodes
static constexpr int E = 8192;        // hyperedges
static constexpr int F = 128;         // feature dim
static constexpr int NP = 20480;      // padded node count (K for gemmB; 1024*20)
static constexpr int NP2 = 20096;     // padded node count for gemmC output planes (157*128)
static constexpr int PREP_BLOCKS = 1024;  // 20 rows each; blocks >= 1000 are pad
static constexpr int PREP_REAL = 1000;
static constexpr int XW_BLOCKS = NP / 8;  // 2560, 8 rows each
static constexpr int SE_BLOCKS = 128;     // folded into gemmB launch (blocks 0..127)
static constexpr int KS_B = 8;        // gemmB split-K
static constexpr int KS_C = 4;        // gemmC split-K

typedef short bf16x8 __attribute__((ext_vector_type(8)));
typedef float f32x4 __attribute__((ext_vector_type(4)));

__device__ __forceinline__ float gelu_erf(float x) {
    return 0.5f * x * (1.0f + erff(x * 0.70710678118654752440f));
}
__device__ __forceinline__ ushort f2bf(float f) {
    unsigned u = __float_as_uint(f);
    return (ushort)((u + 0x7FFFu + ((u >> 16) & 1u)) >> 16);
}
// async global->LDS, 16B per lane (global source per-lane, LDS dest = base + lane*16)
__device__ __forceinline__ void gload16(const void* g, void* lds) {
    __builtin_amdgcn_global_load_lds(
        (const __attribute__((address_space(1))) unsigned int*)g,
        (__attribute__((address_space(3))) unsigned int*)lds, 16, 0, 0);
}

// ---------------- fused: prep (blocks 0..1023) + xw->yT (blocks 1024..3583) ----------------
__global__ __launch_bounds__(256) void k_prep_xw(const float* __restrict__ H,
                                                 float* __restrict__ DeP,
                                                 ushort* __restrict__ Hbs,
                                                 const float* __restrict__ x,
                                                 const float* __restrict__ lin_w,
                                                 const float* __restrict__ lin_b,
                                                 ushort* __restrict__ yT) {
    __shared__ __align__(16) char smem[4096];
    const int tid = threadIdx.x;

    if (blockIdx.x < PREP_BLOCKS) {
        // ================= prep =================
        const int lane = tid & 63, wid = tid >> 6;
        const int r0 = blockIdx.x * 20;
        if (r0 >= N) {        // pad rows [N, NP): Hbs = 0
            uint4 z = make_uint4(0, 0, 0, 0);
            for (int r = 0; r < 20; ++r) {
                ushort* orow = Hbs + (size_t)(r0 + r) * E;
#pragma unroll
                for (int j = 0; j < 4; ++j) *(uint4*)(orow + (j * 256 + tid) * 8) = z;
            }
            return;
        }
        float (*rp)[4] = (float(*)[4])smem;    // [20][4]
        float4 ca[4][2];
#pragma unroll
        for (int j = 0; j < 4; ++j) {
            ca[j][0] = make_float4(0.f, 0.f, 0.f, 0.f);
            ca[j][1] = make_float4(0.f, 0.f, 0.f, 0.f);
        }
        for (int r = 0; r < 20; ++r) {
            const float* row = H + (size_t)(r0 + r) * E;
            float4 va[4], vb[4];
            float rs = 0.f;
#pragma unroll
            for (int j = 0; j < 4; ++j) {
                const float* base = row + (j * 256 + tid) * 8;   // 32B contiguous per thread
                va[j] = *(const float4*)(base);
                vb[j] = *(const float4*)(base + 4);
                ca[j][0].x += va[j].x; ca[j][0].y += va[j].y; ca[j][0].z += va[j].z; ca[j][0].w += va[j].w;
                ca[j][1].x += vb[j].x; ca[j][1].y += vb[j].y; ca[j][1].z += vb[j].z; ca[j][1].w += vb[j].w;
                rs += (va[j].x + va[j].y) + (va[j].z + va[j].w);
                rs += (vb[j].x + vb[j].y) + (vb[j].z + vb[j].w);
            }
#pragma unroll
            for (int off = 32; off > 0; off >>= 1) rs += __shfl_xor(rs, off, 64);
            if (lane == 0) rp[r][wid] = rs;
            __syncthreads();
            float scale = rsqrtf(fmaxf(rp[r][0] + rp[r][1] + rp[r][2] + rp[r][3], 1.f));
            ushort* orow = Hbs + (size_t)(r0 + r) * E;
#pragma unroll
            for (int j = 0; j < 4; ++j) {
                uint4 o;
                o.x = (unsigned)f2bf(va[j].x * scale) | ((unsigned)f2bf(va[j].y * scale) << 16);
                o.y = (unsigned)f2bf(va[j].z * scale) | ((unsigned)f2bf(va[j].w * scale) << 16);
                o.z = (unsigned)f2bf(vb[j].x * scale) | ((unsigned)f2bf(vb[j].y * scale) << 16);
                o.w = (unsigned)f2bf(vb[j].z * scale) | ((unsigned)f2bf(vb[j].w * scale) << 16);
                *(uint4*)(orow + (j * 256 + tid) * 8) = o;       // 16B contiguous store
            }
        }
        float* dp = DeP + (size_t)blockIdx.x * E;
#pragma unroll
        for (int j = 0; j < 4; ++j) {
            *(float4*)(dp + (j * 256 + tid) * 8) = ca[j][0];
            *(float4*)(dp + (j * 256 + tid) * 8 + 4) = ca[j][1];
        }
    } else {
        // ================= xw -> yT (lin_w read directly, row-contiguous per thread) ======
        const int bxx = blockIdx.x - PREP_BLOCKS;
        const int r0 = bxx * 8;
        if (r0 >= N) {        // pad cols of yT
            if (tid < 128) {
                uint4 z = make_uint4(0, 0, 0, 0);
                *(uint4*)(yT + (size_t)tid * NP + r0) = z;
            }
            return;
        }
        float* xs = (float*)smem;              // [8][128] fp32
#pragma unroll
        for (int c = 0; c < 4; ++c) {
            int lin = c * 256 + tid;
            xs[lin] = x[(size_t)r0 * F + lin];
        }
        __syncthreads();
        const int f = tid & 127, half = tid >> 7;    // rows half*4 .. half*4+3
        float b = lin_b[f];
        float a0 = b, a1 = b, a2 = b, a3 = b;
        const float* xr = xs + (half * 4) * F;
        const float* lwr = lin_w + (size_t)f * F;
#pragma unroll 4
        for (int k = 0; k < F; k += 4) {
            float4 lw = *(const float4*)(lwr + k);
            a0 += xr[0 * F + k] * lw.x; a0 += xr[0 * F + k + 1] * lw.y;
            a0 += xr[0 * F + k + 2] * lw.z; a0 += xr[0 * F + k + 3] * lw.w;
            a1 += xr[1 * F + k] * lw.x; a1 += xr[1 * F + k + 1] * lw.y;
            a1 += xr[1 * F + k + 2] * lw.z; a1 += xr[1 * F + k + 3] * lw.w;
            a2 += xr[2 * F + k] * lw.x; a2 += xr[2 * F + k + 1] * lw.y;
            a2 += xr[2 * F + k + 2] * lw.z; a2 += xr[2 * F + k + 3] * lw.w;
            a3 += xr[3 * F + k] * lw.x; a3 += xr[3 * F + k + 1] * lw.y;
            a3 += xr[3 * F + k + 2] * lw.z; a3 += xr[3 * F + k + 3] * lw.w;
        }
        __syncthreads();                        // all xs reads done
        ushort* tile = (ushort*)smem;           // [8][128] bf16
        tile[(half * 4 + 0) * F + f] = f2bf(a0);
        tile[(half * 4 + 1) * F + f] = f2bf(a1);
        tile[(half * 4 + 2) * F + f] = f2bf(a2);
        tile[(half * 4 + 3) * F + f] = f2bf(a3);
        __syncthreads();
        if (tid < 128) {
            unsigned u[4];
#pragma unroll
            for (int qq = 0; qq < 4; ++qq) {
                ushort lo = tile[(qq * 2 + 0) * F + tid];
                ushort hi = tile[(qq * 2 + 1) * F + tid];
                u[qq] = (unsigned)lo | ((unsigned)hi << 16);
            }
            uint4 o = make_uint4(u[0], u[1], u[2], u[3]);
            *(uint4*)(yT + (size_t)tid * NP + r0) = o;
        }
    }
}

// ---------------- tsT[f][e] = bf16(se[e] * sum_ks tB[ks][e][f])  (reduce + transpose) ------
__global__ void k_tst(const float* __restrict__ tB, const float* __restrict__ se,
                      ushort* __restrict__ tsT) {
    __shared__ __align__(16) char tl[8192];
    int tid = threadIdx.x;
    int r0 = (blockIdx.x >> 1) * 64;   // e
    int c0 = (blockIdx.x & 1) * 64;    // f
#pragma unroll
    for (int c = 0; c < 4; ++c) {
        int lin = c * 256 + tid;
        int row = lin >> 4, ch = lin & 15;
        size_t base = (size_t)(r0 + row) * F + c0 + ch * 4;
        float4 v = make_float4(0.f, 0.f, 0.f, 0.f);
#pragma unroll
        for (int ks = 0; ks < KS_B; ++ks) {
            float4 p = *(const float4*)(tB + (size_t)ks * E * F + base);
            v.x += p.x; v.y += p.y; v.z += p.z; v.w += p.w;
        }
        float s = se[r0 + row];
        ushort4 b;
        b.x = f2bf(v.x * s); b.y = f2bf(v.y * s); b.z = f2bf(v.z * s); b.w = f2bf(v.w * s);
        int key = ((row ^ (row >> 3)) & 7) << 4;
        *(ushort4*)(tl + row * 128 + ((ch * 8) ^ key)) = b;
    }
    __syncthreads();
#pragma unroll
    for (int c = 0; c < 2; ++c) {
        int lin = c * 256 + tid;
        int fl = lin >> 3, vch = lin & 7;
        unsigned u[4];
#pragma unroll
        for (int qq = 0; qq < 4; ++qq) {
            int r1 = vch * 8 + qq * 2, r2 = r1 + 1;
            ushort a = *(const ushort*)(tl + r1 * 128 + ((fl * 2) ^ (((r1 ^ (r1 >> 3)) & 7) << 4)));
            ushort b = *(const ushort*)(tl + r2 * 128 + ((fl * 2) ^ (((r2 ^ (r2 >> 3)) & 7) << 4)));
            u[qq] = (unsigned)a | ((unsigned)b << 16);
        }
        uint4 o = make_uint4(u[0], u[1], u[2], u[3]);
        *(uint4*)(tsT + (size_t)(c0 + fl) * E + r0 + vch * 8) = o;
    }
}

// ---------------- gemmB launch: blocks 0..127 = se reduction; 128..639 = gemmB ------------
// se: se[e] = W[e] / clip(sum_p DeP[p][e], 1). Runs first, hides under gemmB.
// gemmB: tB[ks][e][f] = sum_{v in chunk} Hbs[v][e] * yT[f][v]. R10 structure.
__global__ __launch_bounds__(256) void k_gemmB(const ushort* __restrict__ Hbs,
                                               const ushort* __restrict__ yT,
                                               float* __restrict__ tB,
                                               const float* __restrict__ DeP,
                                               const float* __restrict__ W,
                                               float* __restrict__ se) {
    __shared__ __align__(16) char lA[2][16384];   // As[e 128][v 64] bf16, key ((e>>3)&7)<<4
    __shared__ __align__(16) char lB[2][16384];   // Bs[f 128][v 64] bf16, key (f&7)<<4
    const int tid = threadIdx.x;

    if (blockIdx.x < SE_BLOCKS) {
        // ===== se reduction (4-way p-split, 4 independent accumulators) =====
        float (*red)[64] = (float(*)[64])lA;
        const int c = blockIdx.x * 64 + (tid & 63);
        const int pg = tid >> 6;
        float s0 = 0.f, s1 = 0.f, s2 = 0.f, s3 = 0.f;
        int p = pg;
        for (; p + 12 < PREP_REAL; p += 16) {
            s0 += DeP[(size_t)(p +  0) * E + c];
            s1 += DeP[(size_t)(p +  4) * E + c];
            s2 += DeP[(size_t)(p +  8) * E + c];
            s3 += DeP[(size_t)(p + 12) * E + c];
        }
        for (; p < PREP_REAL; p += 4) s0 += DeP[(size_t)p * E + c];
        red[pg][tid & 63] = (s0 + s1) + (s2 + s3);
        __syncthreads();
        if (tid < 64) {
            float d = red[0][tid] + red[1][tid] + red[2][tid] + red[3][tid];
            int e = blockIdx.x * 64 + tid;
            se[e] = W[e] / fmaxf(d, 1.f);
        }
        return;
    }

    const int bx2 = blockIdx.x - SE_BLOCKS;
    const int sw = (bx2 & 7) * 64 + (bx2 >> 3);   // bijective (512 % 8 == 0)
    const int m0 = (sw & 63) * 128;    // e tile
    const int ks = sw >> 6;
    const int k0 = ks * 2560;          // v chunk
    const int lane = tid & 63, w = tid >> 6;
    const int wm = (w & 1) * 64, wn = (w >> 1) * 64;
    const int lrow = lane & 15, g16 = (lane >> 4) * 16;
    const int NSTEP = 40;

    const int vq = tid >> 4;
    const int e8 = (tid & 15) * 8;
    const ushort* pa = Hbs + (size_t)(k0 + vq * 4) * E + m0 + e8;
    const int abase = e8 * 128 + ((vq * 8) ^ ((tid & 7) << 4));

    // B staging via global_load_lds: wave w stages f-rows [w*32, w*32+32)
    const int row8 = lane >> 3, ch8 = lane & 7;
    const ushort* gB = yT + (size_t)(w * 32 + row8) * NP + k0 + ((ch8 ^ row8) * 8);
    const int ldstB = w * 32 * 128;

    int aoff[4][2], boff[4][2];
#pragma unroll
    for (int f = 0; f < 4; ++f)
#pragma unroll
        for (int kk = 0; kk < 2; ++kk) {
            int ma = wm + f * 16 + lrow;
            aoff[f][kk] = ma * 128 + (((kk * 64) + g16) ^ (((ma >> 3) & 7) << 4));
            int nb = wn + f * 16 + lrow;
            boff[f][kk] = nb * 128 + (((kk * 64) + g16) ^ ((nb & 7) << 4));
        }

    f32x4 zero4 = {0.f, 0.f, 0.f, 0.f};
    f32x4 acc[4][4];
#pragma unroll
    for (int i = 0; i < 4; ++i)
#pragma unroll
        for (int j = 0; j < 4; ++j) acc[i][j] = zero4;

    uint4 ra[4];
#pragma unroll
    for (int r = 0; r < 4; ++r) ra[r] = *(const uint4*)(pa + (size_t)r * E);
    {
        const ushort* u0 = (const ushort*)&ra[0];
        const ushort* u1 = (const ushort*)&ra[1];
        const ushort* u2 = (const ushort*)&ra[2];
        const ushort* u3 = (const ushort*)&ra[3];
#pragma unroll
        for (int i = 0; i < 8; ++i) {
            uint2 wv;
            wv.x = (unsigned)u0[i] | ((unsigned)u1[i] << 16);
            wv.y = (unsigned)u2[i] | ((unsigned)u3[i] << 16);
            *(uint2*)(lA[0] + abase + i * 128) = wv;
        }
#pragma unroll
        for (int i = 0; i < 4; ++i)
            gload16(gB + (size_t)i * 8 * NP, lB[0] + ldstB + i * 1024);
    }
    pa += (size_t)64 * E;
#pragma unroll
    for (int r = 0; r < 4; ++r) ra[r] = *(const uint4*)(pa + (size_t)r * E);
    __syncthreads();

    for (int kt = 0; kt < NSTEP; ++kt) {
        const int cur = kt & 1;
        if (kt + 1 < NSTEP) {
            const ushort* u0 = (const ushort*)&ra[0];
            const ushort* u1 = (const ushort*)&ra[1];
            const ushort* u2 = (const ushort*)&ra[2];
            const ushort* u3 = (const ushort*)&ra[3];
#pragma unroll
            for (int i = 0; i < 8; ++i) {
                uint2 wv;
                wv.x = (unsigned)u0[i] | ((unsigned)u1[i] << 16);
                wv.y = (unsigned)u2[i] | ((unsigned)u3[i] << 16);
                *(uint2*)(lA[cur ^ 1] + abase + i * 128) = wv;
            }
            const int koff = (kt + 1) * 64;
#pragma unroll
            for (int i = 0; i < 4; ++i)
                gload16(gB + (size_t)i * 8 * NP + koff, lB[cur ^ 1] + ldstB + i * 1024);
        }
        if (kt + 2 < NSTEP) {
            pa += (size_t)64 * E;
#pragma unroll
            for (int r = 0; r < 4; ++r) ra[r] = *(const uint4*)(pa + (size_t)r * E);
        }
#pragma unroll
        for (int kk = 0; kk < 2; ++kk) {
            bf16x8 av[4], bv[4];
#pragma unroll
            for (int f = 0; f < 4; ++f) av[f] = *(const bf16x8*)(lA[cur] + aoff[f][kk]);
#pragma unroll
            for (int f = 0; f < 4; ++f) bv[f] = *(const bf16x8*)(lB[cur] + boff[f][kk]);
#pragma unroll
            for (int i = 0; i < 4; ++i)
#pragma unroll
                for (int j = 0; j < 4; ++j)
                    acc[i][j] = __builtin_amdgcn_mfma_f32_16x16x32_bf16(av[i], bv[j], acc[i][j], 0, 0, 0);
        }
        if (kt + 1 < NSTEP) __syncthreads();
    }
    float* plane = tB + (size_t)ks * E * F;
    const int orow = (lane >> 4) * 4, ocol = lane & 15;
#pragma unroll
    for (int i = 0; i < 4; ++i)
#pragma unroll
        for (int j = 0; j < 4; ++j) {
            int gm = m0 + wm + i * 16 + orow;
            int gn = wn + j * 16 + ocol;
#pragma unroll
            for (int q = 0; q < 4; ++q)
                plane[(size_t)(gm + q) * F + gn] = acc[i][j][q];
        }
}

// ---------------- gemmC (MFMA): C2P[ks][n][f] = sum_{e in chunk} Hbs[n][e] * tsT[f][e] -----
// BOTH operands via global_load_lds w=16 (linear dest, inv-swz src). Dbuf, 1 barrier/step.
__global__ __launch_bounds__(256) void k_gemmC(const ushort* __restrict__ Hbs,
                                               const ushort* __restrict__ tsT,
                                               float* __restrict__ C2P) {
    __shared__ __align__(16) char lA[2][16384];
    __shared__ __align__(16) char lB[2][16384];
    const int tid = threadIdx.x;
    const int qq_ = 78, rr_ = 4;                     // 628 = 8*78 + 4
    const int xcd = blockIdx.x & 7, idx = blockIdx.x >> 3;
    const int sw = (xcd < rr_ ? xcd * (qq_ + 1) : rr_ * (qq_ + 1) + (xcd - rr_) * qq_) + idx;
    const int m0 = (sw % 157) * 128;
    const int ks = sw / 157;
    const int k0 = ks * 2048;
    const int lane = tid & 63, w = tid >> 6;
    const int wm = (w & 1) * 64, wn = (w >> 1) * 64;
    const int lrow = lane & 15, g16 = (lane >> 4) * 16;
    const int NSTEP = 32;

    const int row8 = lane >> 3, ch8 = lane & 7;
    const ushort* gA = Hbs + (size_t)(m0 + w * 32 + row8) * E + k0 + ((ch8 ^ row8) * 8);
    const ushort* gB = tsT + (size_t)(w * 32 + row8) * E + k0 + ((ch8 ^ row8) * 8);
    const int ldst = w * 32 * 128;

    int aoff[4][2], boff[4][2];
#pragma unroll
    for (int f = 0; f < 4; ++f)
#pragma unroll
        for (int kk = 0; kk < 2; ++kk) {
            int ma = wm + f * 16 + lrow;
            aoff[f][kk] = ma * 128 + (((kk * 64) + g16) ^ ((ma & 7) << 4));
            int nb = wn + f * 16 + lrow;
            boff[f][kk] = nb * 128 + (((kk * 64) + g16) ^ ((nb & 7) << 4));
        }

    f32x4 zero4 = {0.f, 0.f, 0.f, 0.f};
    f32x4 acc[4][4];
#pragma unroll
    for (int i = 0; i < 4; ++i)
#pragma unroll
        for (int j = 0; j < 4; ++j) acc[i][j] = zero4;

#pragma unroll
    for (int i = 0; i < 4; ++i) {
        gload16(gA + (size_t)i * 8 * E, lA[0] + ldst + i * 1024);
        gload16(gB + (size_t)i * 8 * E, lB[0] + ldst + i * 1024);
    }
    __syncthreads();

    for (int kt = 0; kt < NSTEP; ++kt) {
        const int cur = kt & 1;
        if (kt + 1 < NSTEP) {
            const int koff = (kt + 1) * 64;
#pragma unroll
            for (int i = 0; i < 4; ++i) {
                gload16(gA + (size_t)i * 8 * E + koff, lA[cur ^ 1] + ldst + i * 1024);
                gload16(gB + (size_t)i * 8 * E + koff, lB[cur ^ 1] + ldst + i * 1024);
            }
        }
#pragma unroll
        for (int kk = 0; kk < 2; ++kk) {
            bf16x8 av[4], bv[4];
#pragma unroll
            for (int f = 0; f < 4; ++f) av[f] = *(const bf16x8*)(lA[cur] + aoff[f][kk]);
#pragma unroll
            for (int f = 0; f < 4; ++f) bv[f] = *(const bf16x8*)(lB[cur] + boff[f][kk]);
#pragma unroll
            for (int i = 0; i < 4; ++i)
#pragma unroll
                for (int j = 0; j < 4; ++j)
                    acc[i][j] = __builtin_amdgcn_mfma_f32_16x16x32_bf16(av[i], bv[j], acc[i][j], 0, 0, 0);
        }
        if (kt + 1 < NSTEP) __syncthreads();
    }
    float* plane = C2P + (size_t)ks * NP2 * F;
    const int orow = (lane >> 4) * 4, ocol = lane & 15;
#pragma unroll
    for (int i = 0; i < 4; ++i)
#pragma unroll
        for (int j = 0; j < 4; ++j) {
            int gm = m0 + wm + i * 16 + orow;
            int gn = wn + j * 16 + ocol;
#pragma unroll
            for (int q = 0; q < 4; ++q)
                plane[(size_t)(gm + q) * F + gn] = acc[i][j][q];
        }
}

// ---------------- out = gelu(sum_ks C2P[ks][n][f])   (dvis folded into Hbs) ----------------
__global__ void k_fin_out(const float* __restrict__ C2P, float* __restrict__ out) {
    int i4 = blockIdx.x * 256 + threadIdx.x;
    if (i4 < N * F / 4) {
        float4 v = make_float4(0.f, 0.f, 0.f, 0.f);
#pragma unroll
        for (int ks = 0; ks < KS_C; ++ks) {
            float4 p = reinterpret_cast<const float4*>(C2P + (size_t)ks * NP2 * F)[i4];
            v.x += p.x; v.y += p.y; v.z += p.z; v.w += p.w;
        }
        float4 o;
        o.x = gelu_erf(v.x);
        o.y = gelu_erf(v.y);
        o.z = gelu_erf(v.z);
        o.w = gelu_erf(v.w);
        reinterpret_cast<float4*>(out)[i4] = o;
    }
}

extern "C" void kernel_launch(void* const* d_in, const int* in_sizes, int n_in,
                              void* d_out, int out_size, void* d_ws, size_t ws_size,
                              hipStream_t stream) {
    const float* x     = (const float*)d_in[0];
    const float* H     = (const float*)d_in[1];
    const float* W     = (const float*)d_in[2];
    const float* lin_w = (const float*)d_in[3];
    const float* lin_b = (const float*)d_in[4];
    float* out = (float*)d_out;

    // workspace layout (bytes): ~451 MiB
    char* ws = (char*)d_ws;
    ushort* Hbs = (ushort*)ws;                                   // NP*E*2      = 335,544,320
    ushort* yT  = (ushort*)(ws + 335544320);                     // F*NP*2      = 5,242,880
    float*  tB  = (float*) (ws + 340787200);                     // 8*E*F*4     = 33,554,432
    ushort* tsT = (ushort*)(ws + 374341632);                     // F*E*2       = 2,097,152
    float*  C2P = (float*) (ws + 376438784);                     // 4*NP2*F*4   = 41,156,608
    float*  DeP = (float*) (ws + 417595392);                     // 1024*E*4    = 33,554,432
    float*  se  = (float*) (ws + 451149824);                     // E*4

    k_prep_xw<<<PREP_BLOCKS + XW_BLOCKS, 256, 0, stream>>>(H, DeP, Hbs, x, lin_w, lin_b, yT);
    k_gemmB<<<SE_BLOCKS + 64 * KS_B, 256, 0, stream>>>(Hbs, yT, tB, DeP, W, se);
    k_tst<<<(E / 64) * 2, 256, 0, stream>>>(tB, se, tsT);
    k_gemmC<<<157 * KS_C, 256, 0, stream>>>(Hbs, tsT, C2P);
    k_fin_out<<<(N * F / 4 + 255) / 256, 256, 0, stream>>>(C2P, out);
}